// Round 12
// baseline (2708.029 us; speedup 1.0000x reference)
//
#include <hip/hip_runtime.h>

#define B_ROWS  2048
#define T_STEPS 112
#define N1 1300
#define N2 340
#define N3 1400

// per-wave index-list region sizes (entries), 2-wave blocks (worst-case safe)
#define R1 704   // 11 chunks x 64
#define R2 192
#define R3 704

// d_ws float offsets
#define OFF_W2T 0          // [1300][340]
#define OFF_W3T 442000     // [340][1400]
#define OFF_W4T 918000     // [1400][4]
#define OFF_BS1 923600     // 1300
#define OFF_BS2 924900     // 340
#define OFF_BS3 925240     // 1400
#define OFF_BS4 926640     // 4
#define WS_FLOATS 926644

__global__ __launch_bounds__(256) void snn_prep(
    const float* __restrict__ W2, const float* __restrict__ W3, const float* __restrict__ W4,
    const float* __restrict__ b1, const float* __restrict__ bias1,
    const float* __restrict__ b2, const float* __restrict__ bias2,
    const float* __restrict__ b3, const float* __restrict__ bias3,
    const float* __restrict__ b4, const float* __restrict__ bias4,
    float* __restrict__ ws)
{
    for (int idx = blockIdx.x * blockDim.x + threadIdx.x; idx < WS_FLOATS;
         idx += gridDim.x * blockDim.x) {
        float v;
        if (idx < OFF_W3T) {                       // W2T[i][k] = W2[k][i]
            int j = idx; int i = j / N2, k = j % N2;
            v = W2[k * N1 + i];
        } else if (idx < OFF_W4T) {                // W3T[i][k] = W3[k][i]
            int j = idx - OFF_W3T; int i = j / N3, k = j % N3;
            v = W3[k * N2 + i];
        } else if (idx < OFF_BS1) {                // W4T[i][k] = W4[k][i]
            int j = idx - OFF_W4T; int i = j / 4, k = j % 4;
            v = W4[k * N3 + i];
        } else if (idx < OFF_BS2) { int j = idx - OFF_BS1; v = b1[j] + bias1[j]; }
        else if (idx < OFF_BS3)   { int j = idx - OFF_BS2; v = b2[j] + bias2[j]; }
        else if (idx < OFF_BS4)   { int j = idx - OFF_BS3; v = b3[j] + bias3[j]; }
        else                      { int j = idx - OFF_BS4; v = b4[j] + bias4[j]; }
        ws[idx] = v;
    }
}

// Packed fp32 add: one VOP3P for two independent per-component chains.
// Numerically identical to the two scalar adds.
__device__ __forceinline__ float2 pk_add(float2 a, float2 b) {
    float2 d;
    asm("v_pk_add_f32 %0, %1, %2" : "=v"(d) : "v"(a), "v"(b));
    return d;
}
__device__ __forceinline__ void pk_acc4(float4& acc, const float4 r) {
    float2 lo = pk_add(make_float2(acc.x, acc.y), make_float2(r.x, r.y));
    float2 hi = pk_add(make_float2(acc.z, acc.w), make_float2(r.z, r.w));
    acc.x = lo.x; acc.y = lo.y; acc.z = hi.x; acc.w = hi.y;
}

// R8 structure on 2-wave (128-thread) blocks: LDS ~20 KB -> ~7 blocks/CU,
// so latency windows from ~14 independent block-streams overlap per CU
// (R8 had ~2.6). Partial-reduce reads 2 partials/neuron (was 4); barriers
// sync only 2 waves. Own-spike full-row gathers, 2 barriers/step, layer 4
// deferred one step to wave 1. R11 lesson applied: waves/block is a cost,
// blocks/CU is the benefit.
__global__ __launch_bounds__(128, 4) void snn_main(
    const float* __restrict__ x,
    const float* __restrict__ W1,
    const float* __restrict__ ws,
    const float* __restrict__ thr4p,
    float* __restrict__ out)
{
    const int b    = blockIdx.x;
    const int tid  = threadIdx.x;
    const int wave = tid >> 6;
    const int lane = tid & 63;

    const float* __restrict__ W2T = ws + OFF_W2T;
    const float* __restrict__ W3T = ws + OFF_W3T;
    const float* __restrict__ W4T = ws + OFF_W4T;
    const float* __restrict__ bs1 = ws + OFF_BS1;
    const float* __restrict__ bs2 = ws + OFF_BS2;
    const float* __restrict__ bs3 = ws + OFF_BS3;
    const float* __restrict__ bs4 = ws + OFF_BS4;

    __shared__ __align__(16) float pw2[2][340];
    __shared__ __align__(16) float pw3[2][1400];
    __shared__ __align__(16) unsigned short lst1[2 * R1];
    __shared__ __align__(16) unsigned short lst2[2 * R2];
    __shared__ __align__(16) unsigned short lst3[2 * R3];
    __shared__ float h4part[2][4];

    // layer-1 chunk ownership: 21 chunks = 11 (wave 0) + 10 (wave 1)
    const int c1b = wave * 11;
    const int n1  = 11 - wave;

    float mem1[11] = {0.f,0.f,0.f,0.f,0.f,0.f,0.f,0.f,0.f,0.f,0.f};
    float mem2[3]  = {0.f,0.f,0.f};
    float mem3[11] = {0.f,0.f,0.f,0.f,0.f,0.f,0.f,0.f,0.f,0.f,0.f};
    float mem4 = 0.f;
    float cnt  = 0.f;
    const float thr4 = thr4p[0];

    const float4* __restrict__ xv4 = (const float4*)x;
    const float4* __restrict__ W1v = (const float4*)W1;

    // ---- t-invariant setup ----
    float bsv1[11];
    #pragma unroll
    for (int u = 0; u < 11; ++u) {
        const int k1 = (c1b + u) * 64 + lane;
        bsv1[u] = ((u < n1) && (k1 < N1)) ? bs1[k1] : 0.f;
    }
    float bs2v[3];
    #pragma unroll
    for (int k = 0; k < 3; ++k) {
        const bool valid = (k < 2) || (tid < 84);
        bs2v[k] = valid ? bs2[tid + 128 * k] : 0.f;
    }
    float bs3v[11];
    #pragma unroll
    for (int k = 0; k < 11; ++k) {
        const bool valid = (k < 10) || (tid < 120);
        bs3v[k] = valid ? bs3[tid + 128 * k] : 0.f;
    }
    const float bs4v = bs4[lane & 3];

    // clamped secondary-chunk offsets (inactive lanes load valid garbage,
    // never stored)
    const int so2 = (lane < 21) ? 4 * lane : 80;     // layer-2 cols 256..339
    const int so3 = (lane < 30) ? 4 * lane : 116;    // layer-3 cols 1280..1399

    for (int t = 0; t < T_STEPS; ++t) {
        float4 xv = xv4[b * T_STEPS + t];
        const float x0 = xv.x / 50.0f + 0.001f;
        const float x1 = xv.y / 50.0f + 0.001f;
        const float x2 = xv.z / 50.0f + 0.001f;
        const float x3 = xv.w / 50.0f + 0.001f;

        // ---------- P1: layer 1 + LIF + own-wave list ----------
        unsigned cnt1w = 0;
        #pragma unroll
        for (int u = 0; u < 11; ++u) {
            if (u < n1) {
                const int k1 = (c1b + u) * 64 + lane;
                const bool valid = (k1 < N1);
                float h = 0.f;
                if (valid) {
                    float4 wv = W1v[k1];
                    h = bsv1[u] + wv.x * x0 + wv.y * x1 + wv.z * x2 + wv.w * x3;
                }
                float m = mem1[u];
                const float r = (m > 1.0f) ? 1.0f : 0.0f;
                m = 0.9f * m + h - r;
                mem1[u] = m;
                const bool sp = valid && (m > 1.0f);
                const unsigned long long bal = __ballot(sp);
                if (sp) {
                    const int pos = (int)cnt1w + (int)__popcll(bal & ((1ull << lane) - 1ull));
                    lst1[wave * R1 + pos] = (unsigned short)k1;
                }
                cnt1w += (unsigned)__popcll(bal);
            }
        }

        // ---------- P2: layer-2 gather (own spikes, full rows) ----------
        // unroll 4 + depth-1 pipeline (R8's proven shape)
        {
            float4 accA = {0.f,0.f,0.f,0.f};
            float4 accB = {0.f,0.f,0.f,0.f};
            const unsigned short* L = lst1 + wave * R1;
            const float* baseA = W2T + 4 * lane;
            const float* baseB = W2T + 256 + so2;
            const int n = (int)cnt1w;
            int j = 0;
            if (n >= 4) {
                ushort4 i0 = *(const ushort4*)(L);
                int o0 = (int)i0.x * N2, o1 = (int)i0.y * N2;
                int o2 = (int)i0.z * N2, o3 = (int)i0.w * N2;
                float4 rA0 = *(const float4*)(baseA + o0);
                float4 rA1 = *(const float4*)(baseA + o1);
                float4 rA2 = *(const float4*)(baseA + o2);
                float4 rA3 = *(const float4*)(baseA + o3);
                float4 rB0 = *(const float4*)(baseB + o0);
                float4 rB1 = *(const float4*)(baseB + o1);
                float4 rB2 = *(const float4*)(baseB + o2);
                float4 rB3 = *(const float4*)(baseB + o3);
                for (j = 4; j + 4 <= n; j += 4) {
                    ushort4 i1 = *(const ushort4*)(L + j);
                    const int p0 = (int)i1.x * N2, p1 = (int)i1.y * N2;
                    const int p2 = (int)i1.z * N2, p3 = (int)i1.w * N2;
                    float4 sA0 = *(const float4*)(baseA + p0);
                    float4 sA1 = *(const float4*)(baseA + p1);
                    float4 sA2 = *(const float4*)(baseA + p2);
                    float4 sA3 = *(const float4*)(baseA + p3);
                    float4 sB0 = *(const float4*)(baseB + p0);
                    float4 sB1 = *(const float4*)(baseB + p1);
                    float4 sB2 = *(const float4*)(baseB + p2);
                    float4 sB3 = *(const float4*)(baseB + p3);
                    pk_acc4(accA, rA0); pk_acc4(accB, rB0);
                    pk_acc4(accA, rA1); pk_acc4(accB, rB1);
                    pk_acc4(accA, rA2); pk_acc4(accB, rB2);
                    pk_acc4(accA, rA3); pk_acc4(accB, rB3);
                    rA0 = sA0; rA1 = sA1; rA2 = sA2; rA3 = sA3;
                    rB0 = sB0; rB1 = sB1; rB2 = sB2; rB3 = sB3;
                }
                pk_acc4(accA, rA0); pk_acc4(accB, rB0);
                pk_acc4(accA, rA1); pk_acc4(accB, rB1);
                pk_acc4(accA, rA2); pk_acc4(accB, rB2);
                pk_acc4(accA, rA3); pk_acc4(accB, rB3);
            }
            for (; j < n; ++j) {
                const int o = (int)L[j] * N2;
                float4 rA = *(const float4*)(baseA + o);
                float4 rB = *(const float4*)(baseB + o);
                pk_acc4(accA, rA); pk_acc4(accB, rB);
            }
            *(float4*)&pw2[wave][4 * lane] = accA;
            if (lane < 21) *(float4*)&pw2[wave][256 + 4 * lane] = accB;
        }
        __syncthreads();  // B1: pw2 ready (also fences h4part of t-1)

        // ---------- deferred layer-4 combine for step t-1 (wave 1) ----------
        if (wave == 1 && t > 0) {
            float h4 = bs4v + h4part[0][lane & 3];
            h4 += h4part[1][lane & 3];
            float m4 = mem4;
            const float r4 = (m4 > thr4) ? thr4 : 0.f;
            m4 = 0.9f * m4 + h4 - r4;
            mem4 = m4;
            const float s4 = (m4 > thr4) ? 1.f : 0.f;
            if (lane < 4) {
                out[8192 + (b * T_STEPS + (t - 1)) * 4 + lane] = s4;
                cnt += s4;
            }
        }

        // ---------- P3: LIF-2 (thread owns tid+128k) + own-wave list ----------
        unsigned cnt2w = 0;
        #pragma unroll
        for (int k = 0; k < 3; ++k) {
            const bool valid = (k < 2) || (tid < 84);
            const int n = tid + 128 * k;
            float h = 0.f;
            if (valid) h = pw2[0][n] + pw2[1][n] + bs2v[k];
            float m = mem2[k];
            const float r = (m > 1.0f) ? 1.0f : 0.0f;
            m = 0.9f * m + h - r;
            mem2[k] = m;
            const bool sp = valid && (m > 1.0f);
            const unsigned long long bal = __ballot(sp);
            if (sp) {
                const int pos = (int)cnt2w + (int)__popcll(bal & ((1ull << lane) - 1ull));
                lst2[wave * R2 + pos] = (unsigned short)n;
            }
            cnt2w += (unsigned)__popcll(bal);
        }

        // ---------- P4: layer-3 gather (own spikes, full rows, unroll 2) ----------
        {
            float4 acc3[6];
            #pragma unroll
            for (int c = 0; c < 6; ++c) acc3[c] = (float4){0.f,0.f,0.f,0.f};
            const unsigned short* L = lst2 + wave * R2;
            int j = 0;
            for (; j + 2 <= (int)cnt2w; j += 2) {
                ushort2 ii = *(const ushort2*)(L + j);
                const float* ra = W3T + (int)ii.x * N3;
                const float* rb = W3T + (int)ii.y * N3;
                float4 a0 = *(const float4*)(ra + 4*lane);
                float4 a1 = *(const float4*)(ra + 256 + 4*lane);
                float4 a2 = *(const float4*)(ra + 512 + 4*lane);
                float4 a3 = *(const float4*)(ra + 768 + 4*lane);
                float4 a4 = *(const float4*)(ra + 1024 + 4*lane);
                float4 a5 = *(const float4*)(ra + 1280 + so3);
                float4 b0 = *(const float4*)(rb + 4*lane);
                float4 b1_ = *(const float4*)(rb + 256 + 4*lane);
                float4 b2_ = *(const float4*)(rb + 512 + 4*lane);
                float4 b3_ = *(const float4*)(rb + 768 + 4*lane);
                float4 b4_ = *(const float4*)(rb + 1024 + 4*lane);
                float4 b5_ = *(const float4*)(rb + 1280 + so3);
                pk_acc4(acc3[0], a0); pk_acc4(acc3[1], a1); pk_acc4(acc3[2], a2);
                pk_acc4(acc3[3], a3); pk_acc4(acc3[4], a4); pk_acc4(acc3[5], a5);
                pk_acc4(acc3[0], b0); pk_acc4(acc3[1], b1_); pk_acc4(acc3[2], b2_);
                pk_acc4(acc3[3], b3_); pk_acc4(acc3[4], b4_); pk_acc4(acc3[5], b5_);
            }
            for (; j < (int)cnt2w; ++j) {
                const float* ra = W3T + (int)L[j] * N3;
                float4 a0 = *(const float4*)(ra + 4*lane);
                float4 a1 = *(const float4*)(ra + 256 + 4*lane);
                float4 a2 = *(const float4*)(ra + 512 + 4*lane);
                float4 a3 = *(const float4*)(ra + 768 + 4*lane);
                float4 a4 = *(const float4*)(ra + 1024 + 4*lane);
                float4 a5 = *(const float4*)(ra + 1280 + so3);
                pk_acc4(acc3[0], a0); pk_acc4(acc3[1], a1); pk_acc4(acc3[2], a2);
                pk_acc4(acc3[3], a3); pk_acc4(acc3[4], a4); pk_acc4(acc3[5], a5);
            }
            #pragma unroll
            for (int c = 0; c < 5; ++c)
                *(float4*)&pw3[wave][c * 256 + 4 * lane] = acc3[c];
            if (lane < 30) *(float4*)&pw3[wave][1280 + 4 * lane] = acc3[5];
        }
        __syncthreads();  // B2: pw3 ready

        // ---------- P5: LIF-3 (thread owns tid+128k) + own list + L4 partials ----------
        {
            unsigned cnt3w = 0;
            #pragma unroll
            for (int k = 0; k < 11; ++k) {
                const bool valid = (k < 10) || (tid < 120);
                const int n = tid + 128 * k;
                float h = 0.f;
                if (valid) h = pw3[0][n] + pw3[1][n] + bs3v[k];
                float m = mem3[k];
                const float r = (m > 1.0f) ? 1.0f : 0.0f;
                m = 0.9f * m + h - r;
                mem3[k] = m;
                const bool sp = valid && (m > 1.0f);
                const unsigned long long bal = __ballot(sp);
                if (sp) {
                    const int pos = (int)cnt3w + (int)__popcll(bal & ((1ull << lane) - 1ull));
                    lst3[wave * R3 + pos] = (unsigned short)n;
                }
                cnt3w += (unsigned)__popcll(bal);
            }
            // layer-4 partials from own spikes (wave-local lockstep)
            float h4p = 0.f;
            const unsigned short* L = lst3 + wave * R3;
            const int o4 = lane & 3;
            int j = 0;
            for (; j + 4 <= (int)cnt3w; j += 4) {
                ushort4 ii = *(const ushort4*)(L + j);
                float t0 = W4T[4 * (int)ii.x + o4];
                float t1 = W4T[4 * (int)ii.y + o4];
                float t2 = W4T[4 * (int)ii.z + o4];
                float t3 = W4T[4 * (int)ii.w + o4];
                h4p += t0; h4p += t1; h4p += t2; h4p += t3;
            }
            for (; j < (int)cnt3w; ++j) h4p += W4T[4 * (int)L[j] + o4];
            if (lane < 4) h4part[wave][lane] = h4p;
        }
        // no barrier: h4part consumed by wave 1 after B1 of t+1; pw2 rewrite
        // at P2(t+1) is fenced from P3(t) readers by B2(t).
    }

    __syncthreads();  // fence h4part of final step
    if (wave == 1) {
        float h4 = bs4v + h4part[0][lane & 3];
        h4 += h4part[1][lane & 3];
        float m4 = mem4;
        const float r4 = (m4 > thr4) ? thr4 : 0.f;
        m4 = 0.9f * m4 + h4 - r4;
        const float s4 = (m4 > thr4) ? 1.f : 0.f;
        if (lane < 4) {
            out[8192 + (b * T_STEPS + (T_STEPS - 1)) * 4 + lane] = s4;
            cnt += s4;
            out[b * 4 + lane] = cnt;
        }
    }
}

extern "C" void kernel_launch(void* const* d_in, const int* in_sizes, int n_in,
                              void* d_out, int out_size, void* d_ws, size_t ws_size,
                              hipStream_t stream)
{
    const float* x     = (const float*)d_in[0];
    const float* W1    = (const float*)d_in[1];
    const float* b1    = (const float*)d_in[2];
    const float* bias1 = (const float*)d_in[3];
    const float* W2    = (const float*)d_in[4];
    const float* b2    = (const float*)d_in[5];
    const float* bias2 = (const float*)d_in[6];
    const float* W3    = (const float*)d_in[7];
    const float* b3    = (const float*)d_in[8];
    const float* bias3 = (const float*)d_in[9];
    const float* W4    = (const float*)d_in[10];
    const float* b4    = (const float*)d_in[11];
    const float* bias4 = (const float*)d_in[12];
    const float* thr4  = (const float*)d_in[13];
    float* out = (float*)d_out;
    float* ws  = (float*)d_ws;

    hipLaunchKernelGGL(snn_prep, dim3(1024), dim3(256), 0, stream,
                       W2, W3, W4, b1, bias1, b2, bias2, b3, bias3, b4, bias4, ws);
    hipLaunchKernelGGL(snn_main, dim3(B_ROWS), dim3(128), 0, stream,
                       x, W1, ws, thr4, out);
}

// Round 13
// 1943.845 us; speedup vs baseline: 1.3931x; 1.3931x over previous
//
#include <hip/hip_runtime.h>

#define B_ROWS  2048
#define T_STEPS 112
#define N1 1300
#define N2 340
#define N3 1400

// per-wave index-list region sizes (entries)
#define R1 384
#define R2 96
#define R3 384

// d_ws float offsets
#define OFF_W2T 0          // [1300][340]
#define OFF_W3T 442000     // [340][1400]
#define OFF_W4T 918000     // [1400][4]
#define OFF_BS1 923600     // 1300
#define OFF_BS2 924900     // 340
#define OFF_BS3 925240     // 1400
#define OFF_BS4 926640     // 4
#define WS_FLOATS 926644

__global__ __launch_bounds__(256) void snn_prep(
    const float* __restrict__ W2, const float* __restrict__ W3, const float* __restrict__ W4,
    const float* __restrict__ b1, const float* __restrict__ bias1,
    const float* __restrict__ b2, const float* __restrict__ bias2,
    const float* __restrict__ b3, const float* __restrict__ bias3,
    const float* __restrict__ b4, const float* __restrict__ bias4,
    float* __restrict__ ws)
{
    for (int idx = blockIdx.x * blockDim.x + threadIdx.x; idx < WS_FLOATS;
         idx += gridDim.x * blockDim.x) {
        float v;
        if (idx < OFF_W3T) {                       // W2T[i][k] = W2[k][i]
            int j = idx; int i = j / N2, k = j % N2;
            v = W2[k * N1 + i];
        } else if (idx < OFF_W4T) {                // W3T[i][k] = W3[k][i]
            int j = idx - OFF_W3T; int i = j / N3, k = j % N3;
            v = W3[k * N2 + i];
        } else if (idx < OFF_BS1) {                // W4T[i][k] = W4[k][i]
            int j = idx - OFF_W4T; int i = j / 4, k = j % 4;
            v = W4[k * N3 + i];
        } else if (idx < OFF_BS2) { int j = idx - OFF_BS1; v = b1[j] + bias1[j]; }
        else if (idx < OFF_BS3)   { int j = idx - OFF_BS2; v = b2[j] + bias2[j]; }
        else if (idx < OFF_BS4)   { int j = idx - OFF_BS3; v = b3[j] + bias3[j]; }
        else                      { int j = idx - OFF_BS4; v = b4[j] + bias4[j]; }
        ws[idx] = v;
    }
}

// Packed fp32 add: one VOP3P for two independent per-component chains.
// Numerically identical to the two scalar adds.
__device__ __forceinline__ float2 pk_add(float2 a, float2 b) {
    float2 d;
    asm("v_pk_add_f32 %0, %1, %2" : "=v"(d) : "v"(a), "v"(b));
    return d;
}
__device__ __forceinline__ void pk_acc4(float4& acc, const float4 r) {
    float2 lo = pk_add(make_float2(acc.x, acc.y), make_float2(r.x, r.y));
    float2 hi = pk_add(make_float2(acc.z, acc.w), make_float2(r.z, r.w));
    acc.x = lo.x; acc.y = lo.y; acc.z = hi.x; acc.w = hi.y;
}

// R8 (best: 2015 us) + two zero-risk latency-window removals:
//  (1) W1 rows preloaded into registers before the t-loop (addresses are
//      t-invariant) -> P1 is pure VALU, ~6 fewer L2 windows/step;
//  (2) x(t+1) prefetched right after x(t) is consumed.
// +28 VGPR on a measured 84 -> ~112, inside the <=128 occupancy quantum.
__global__ __launch_bounds__(256, 3) void snn_main(
    const float* __restrict__ x,
    const float* __restrict__ W1,
    const float* __restrict__ ws,
    const float* __restrict__ thr4p,
    float* __restrict__ out)
{
    const int b    = blockIdx.x;
    const int tid  = threadIdx.x;
    const int wave = tid >> 6;
    const int lane = tid & 63;

    const float* __restrict__ W2T = ws + OFF_W2T;
    const float* __restrict__ W3T = ws + OFF_W3T;
    const float* __restrict__ W4T = ws + OFF_W4T;
    const float* __restrict__ bs1 = ws + OFF_BS1;
    const float* __restrict__ bs2 = ws + OFF_BS2;
    const float* __restrict__ bs3 = ws + OFF_BS3;
    const float* __restrict__ bs4 = ws + OFF_BS4;

    __shared__ __align__(16) float pw2[4][340];
    __shared__ __align__(16) float pw3[4][1400];
    __shared__ __align__(16) unsigned short lst1[4 * R1];
    __shared__ __align__(16) unsigned short lst2[4 * R2];
    __shared__ __align__(16) unsigned short lst3[4 * R3];
    __shared__ float h4part[4][4];

    // layer-1 chunk ownership: 21 chunks = 6+5+5+5
    const int c1b = (wave == 0) ? 0 : (wave == 1) ? 6 : (wave == 2) ? 11 : 16;
    const int n1  = (wave == 0) ? 6 : 5;

    float mem1[6] = {0.f,0.f,0.f,0.f,0.f,0.f};
    float mem2[2] = {0.f,0.f};
    float mem3[6] = {0.f,0.f,0.f,0.f,0.f,0.f};
    float mem4 = 0.f;
    float cnt  = 0.f;
    const float thr4 = thr4p[0];

    const float4* __restrict__ xv4 = (const float4*)x;
    const float4* __restrict__ W1v = (const float4*)W1;

    // ---- t-invariant setup ----
    int  k1v[6]; bool val1[6]; float bsv1[6];
    float4 w1r[6];
    #pragma unroll
    for (int u = 0; u < 6; ++u) {
        k1v[u] = (c1b + u) * 64 + lane;
        val1[u] = (u < n1) && (k1v[u] < N1);
        bsv1[u] = val1[u] ? bs1[k1v[u]] : 0.f;
        w1r[u]  = val1[u] ? W1v[k1v[u]] : (float4){0.f,0.f,0.f,0.f};  // W1 row preload
    }
    const bool  has2  = (tid < 84);            // owns layer-2 neuron tid+256
    const float bs2v0 = bs2[tid];
    const float bs2v1 = has2 ? bs2[tid + 256] : 0.f;
    float bs3v[6];
    #pragma unroll
    for (int k = 0; k < 5; ++k) bs3v[k] = bs3[tid + 256 * k];
    bs3v[5] = (tid < 120) ? bs3[tid + 1280] : 0.f;
    const float bs4v = bs4[lane & 3];

    // clamped secondary-chunk offsets (inactive lanes load valid garbage,
    // never stored)
    const int so2 = (lane < 21) ? 4 * lane : 80;     // layer-2 cols 256..339
    const int so3 = (lane < 30) ? 4 * lane : 116;    // layer-3 cols 1280..1399

    float4 xv_n = xv4[b * T_STEPS];                  // prefetch x(0)

    for (int t = 0; t < T_STEPS; ++t) {
        const float4 xv = xv_n;
        if (t + 1 < T_STEPS) xv_n = xv4[b * T_STEPS + t + 1];  // lands during this step
        const float x0 = xv.x / 50.0f + 0.001f;
        const float x1 = xv.y / 50.0f + 0.001f;
        const float x2 = xv.z / 50.0f + 0.001f;
        const float x3 = xv.w / 50.0f + 0.001f;

        // ---------- P1: layer 1 (register-resident W1) + LIF + own-wave list ----------
        unsigned cnt1w = 0;
        #pragma unroll
        for (int u = 0; u < 6; ++u) {
            if (u < n1) {
                float h = 0.f;
                if (val1[u]) {
                    h = bsv1[u] + w1r[u].x * x0 + w1r[u].y * x1
                                + w1r[u].z * x2 + w1r[u].w * x3;
                }
                float m = mem1[u];
                const float r = (m > 1.0f) ? 1.0f : 0.0f;
                m = 0.9f * m + h - r;
                mem1[u] = m;
                const bool sp = val1[u] && (m > 1.0f);
                const unsigned long long bal = __ballot(sp);
                if (sp) {
                    const int pos = (int)cnt1w + (int)__popcll(bal & ((1ull << lane) - 1ull));
                    lst1[wave * R1 + pos] = (unsigned short)k1v[u];
                }
                cnt1w += (unsigned)__popcll(bal);
            }
        }

        // ---------- P2: layer-2 gather (own spikes, full rows) ----------
        // depth-1 software pipeline, unroll 4 (R8's proven shape)
        {
            float4 accA = {0.f,0.f,0.f,0.f};
            float4 accB = {0.f,0.f,0.f,0.f};
            const unsigned short* L = lst1 + wave * R1;
            const float* baseA = W2T + 4 * lane;
            const float* baseB = W2T + 256 + so2;
            const int n = (int)cnt1w;
            int j = 0;
            if (n >= 4) {
                ushort4 i0 = *(const ushort4*)(L);
                int o0 = (int)i0.x * N2, o1 = (int)i0.y * N2;
                int o2 = (int)i0.z * N2, o3 = (int)i0.w * N2;
                float4 rA0 = *(const float4*)(baseA + o0);
                float4 rA1 = *(const float4*)(baseA + o1);
                float4 rA2 = *(const float4*)(baseA + o2);
                float4 rA3 = *(const float4*)(baseA + o3);
                float4 rB0 = *(const float4*)(baseB + o0);
                float4 rB1 = *(const float4*)(baseB + o1);
                float4 rB2 = *(const float4*)(baseB + o2);
                float4 rB3 = *(const float4*)(baseB + o3);
                for (j = 4; j + 4 <= n; j += 4) {
                    ushort4 i1 = *(const ushort4*)(L + j);
                    const int p0 = (int)i1.x * N2, p1 = (int)i1.y * N2;
                    const int p2 = (int)i1.z * N2, p3 = (int)i1.w * N2;
                    float4 sA0 = *(const float4*)(baseA + p0);
                    float4 sA1 = *(const float4*)(baseA + p1);
                    float4 sA2 = *(const float4*)(baseA + p2);
                    float4 sA3 = *(const float4*)(baseA + p3);
                    float4 sB0 = *(const float4*)(baseB + p0);
                    float4 sB1 = *(const float4*)(baseB + p1);
                    float4 sB2 = *(const float4*)(baseB + p2);
                    float4 sB3 = *(const float4*)(baseB + p3);
                    pk_acc4(accA, rA0); pk_acc4(accB, rB0);
                    pk_acc4(accA, rA1); pk_acc4(accB, rB1);
                    pk_acc4(accA, rA2); pk_acc4(accB, rB2);
                    pk_acc4(accA, rA3); pk_acc4(accB, rB3);
                    rA0 = sA0; rA1 = sA1; rA2 = sA2; rA3 = sA3;
                    rB0 = sB0; rB1 = sB1; rB2 = sB2; rB3 = sB3;
                }
                pk_acc4(accA, rA0); pk_acc4(accB, rB0);
                pk_acc4(accA, rA1); pk_acc4(accB, rB1);
                pk_acc4(accA, rA2); pk_acc4(accB, rB2);
                pk_acc4(accA, rA3); pk_acc4(accB, rB3);
            }
            for (; j < n; ++j) {
                const int o = (int)L[j] * N2;
                float4 rA = *(const float4*)(baseA + o);
                float4 rB = *(const float4*)(baseB + o);
                pk_acc4(accA, rA); pk_acc4(accB, rB);
            }
            *(float4*)&pw2[wave][4 * lane] = accA;
            if (lane < 21) *(float4*)&pw2[wave][256 + 4 * lane] = accB;
        }
        __syncthreads();  // B1: pw2 ready (also fences h4part of t-1)

        // ---------- deferred layer-4 combine for step t-1 (wave 3) ----------
        if (wave == 3 && t > 0) {
            float h4 = bs4v + h4part[0][lane & 3];
            h4 += h4part[1][lane & 3];
            h4 += h4part[2][lane & 3];
            h4 += h4part[3][lane & 3];
            float m4 = mem4;
            const float r4 = (m4 > thr4) ? thr4 : 0.f;
            m4 = 0.9f * m4 + h4 - r4;
            mem4 = m4;
            const float s4 = (m4 > thr4) ? 1.f : 0.f;
            if (lane < 4) {
                out[8192 + (b * T_STEPS + (t - 1)) * 4 + lane] = s4;
                cnt += s4;
            }
        }

        // ---------- P3: LIF-2 (thread-linear) + own-wave list ----------
        unsigned cnt2w = 0;
        {
            const float h0 = pw2[0][tid] + pw2[1][tid] + pw2[2][tid] + pw2[3][tid] + bs2v0;
            float m = mem2[0];
            const float r = (m > 1.0f) ? 1.0f : 0.0f;
            m = 0.9f * m + h0 - r;
            mem2[0] = m;
            const bool sp0 = (m > 1.0f);
            const unsigned long long bal0 = __ballot(sp0);
            if (sp0) {
                const int pos = (int)__popcll(bal0 & ((1ull << lane) - 1ull));
                lst2[wave * R2 + pos] = (unsigned short)tid;
            }
            cnt2w += (unsigned)__popcll(bal0);

            float h1 = 0.f;
            if (has2) h1 = pw2[0][tid+256] + pw2[1][tid+256] + pw2[2][tid+256] + pw2[3][tid+256] + bs2v1;
            float m1v = mem2[1];
            const float r1v = (m1v > 1.0f) ? 1.0f : 0.0f;
            m1v = 0.9f * m1v + h1 - r1v;
            mem2[1] = m1v;
            const bool sp1 = has2 && (m1v > 1.0f);
            const unsigned long long bal1 = __ballot(sp1);
            if (sp1) {
                const int pos = (int)cnt2w + (int)__popcll(bal1 & ((1ull << lane) - 1ull));
                lst2[wave * R2 + pos] = (unsigned short)(tid + 256);
            }
            cnt2w += (unsigned)__popcll(bal1);
        }

        // ---------- P4: layer-3 gather (own spikes, full rows, pk adds) ----------
        {
            float4 acc3[6];
            #pragma unroll
            for (int c = 0; c < 6; ++c) acc3[c] = (float4){0.f,0.f,0.f,0.f};
            const unsigned short* L = lst2 + wave * R2;
            int j = 0;
            for (; j + 2 <= (int)cnt2w; j += 2) {
                ushort2 ii = *(const ushort2*)(L + j);
                const float* ra = W3T + (int)ii.x * N3;
                const float* rb = W3T + (int)ii.y * N3;
                float4 a0 = *(const float4*)(ra + 4*lane);
                float4 a1 = *(const float4*)(ra + 256 + 4*lane);
                float4 a2 = *(const float4*)(ra + 512 + 4*lane);
                float4 a3 = *(const float4*)(ra + 768 + 4*lane);
                float4 a4 = *(const float4*)(ra + 1024 + 4*lane);
                float4 a5 = *(const float4*)(ra + 1280 + so3);
                float4 b0 = *(const float4*)(rb + 4*lane);
                float4 b1_ = *(const float4*)(rb + 256 + 4*lane);
                float4 b2_ = *(const float4*)(rb + 512 + 4*lane);
                float4 b3_ = *(const float4*)(rb + 768 + 4*lane);
                float4 b4_ = *(const float4*)(rb + 1024 + 4*lane);
                float4 b5_ = *(const float4*)(rb + 1280 + so3);
                pk_acc4(acc3[0], a0); pk_acc4(acc3[1], a1); pk_acc4(acc3[2], a2);
                pk_acc4(acc3[3], a3); pk_acc4(acc3[4], a4); pk_acc4(acc3[5], a5);
                pk_acc4(acc3[0], b0); pk_acc4(acc3[1], b1_); pk_acc4(acc3[2], b2_);
                pk_acc4(acc3[3], b3_); pk_acc4(acc3[4], b4_); pk_acc4(acc3[5], b5_);
            }
            for (; j < (int)cnt2w; ++j) {
                const float* ra = W3T + (int)L[j] * N3;
                float4 a0 = *(const float4*)(ra + 4*lane);
                float4 a1 = *(const float4*)(ra + 256 + 4*lane);
                float4 a2 = *(const float4*)(ra + 512 + 4*lane);
                float4 a3 = *(const float4*)(ra + 768 + 4*lane);
                float4 a4 = *(const float4*)(ra + 1024 + 4*lane);
                float4 a5 = *(const float4*)(ra + 1280 + so3);
                pk_acc4(acc3[0], a0); pk_acc4(acc3[1], a1); pk_acc4(acc3[2], a2);
                pk_acc4(acc3[3], a3); pk_acc4(acc3[4], a4); pk_acc4(acc3[5], a5);
            }
            #pragma unroll
            for (int c = 0; c < 5; ++c)
                *(float4*)&pw3[wave][c * 256 + 4 * lane] = acc3[c];
            if (lane < 30) *(float4*)&pw3[wave][1280 + 4 * lane] = acc3[5];
        }
        __syncthreads();  // B2: pw3 ready

        // ---------- P5: LIF-3 + own list + layer-4 partial gather ----------
        {
            unsigned cnt3w = 0;
            #pragma unroll
            for (int k = 0; k < 6; ++k) {
                const bool valid = (k < 5) || (tid < 120);
                const int n = tid + 256 * k;
                float h = 0.f;
                if (valid) h = pw3[0][n] + pw3[1][n] + pw3[2][n] + pw3[3][n] + bs3v[k];
                float m = mem3[k];
                const float r = (m > 1.0f) ? 1.0f : 0.0f;
                m = 0.9f * m + h - r;
                mem3[k] = m;
                const bool sp = valid && (m > 1.0f);
                const unsigned long long bal = __ballot(sp);
                if (sp) {
                    const int pos = (int)cnt3w + (int)__popcll(bal & ((1ull << lane) - 1ull));
                    lst3[wave * R3 + pos] = (unsigned short)n;
                }
                cnt3w += (unsigned)__popcll(bal);
            }
            // layer-4 partials from own spikes (wave-local)
            float h4p = 0.f;
            const unsigned short* L = lst3 + wave * R3;
            const int o4 = lane & 3;
            int j = 0;
            for (; j + 4 <= (int)cnt3w; j += 4) {
                ushort4 ii = *(const ushort4*)(L + j);
                float t0 = W4T[4 * (int)ii.x + o4];
                float t1 = W4T[4 * (int)ii.y + o4];
                float t2 = W4T[4 * (int)ii.z + o4];
                float t3 = W4T[4 * (int)ii.w + o4];
                h4p += t0; h4p += t1; h4p += t2; h4p += t3;
            }
            for (; j < (int)cnt3w; ++j) h4p += W4T[4 * (int)L[j] + o4];
            if (lane < 4) h4part[wave][lane] = h4p;
        }
        // no barrier: next fence is B1 of t+1, which publishes h4part to wave 3
    }

    __syncthreads();  // fence h4part of final step
    if (wave == 3) {
        float h4 = bs4v + h4part[0][lane & 3];
        h4 += h4part[1][lane & 3];
        h4 += h4part[2][lane & 3];
        h4 += h4part[3][lane & 3];
        float m4 = mem4;
        const float r4 = (m4 > thr4) ? thr4 : 0.f;
        m4 = 0.9f * m4 + h4 - r4;
        const float s4 = (m4 > thr4) ? 1.f : 0.f;
        if (lane < 4) {
            out[8192 + (b * T_STEPS + (T_STEPS - 1)) * 4 + lane] = s4;
            cnt += s4;
            out[b * 4 + lane] = cnt;
        }
    }
}

extern "C" void kernel_launch(void* const* d_in, const int* in_sizes, int n_in,
                              void* d_out, int out_size, void* d_ws, size_t ws_size,
                              hipStream_t stream)
{
    const float* x     = (const float*)d_in[0];
    const float* W1    = (const float*)d_in[1];
    const float* b1    = (const float*)d_in[2];
    const float* bias1 = (const float*)d_in[3];
    const float* W2    = (const float*)d_in[4];
    const float* b2    = (const float*)d_in[5];
    const float* bias2 = (const float*)d_in[6];
    const float* W3    = (const float*)d_in[7];
    const float* b3    = (const float*)d_in[8];
    const float* bias3 = (const float*)d_in[9];
    const float* W4    = (const float*)d_in[10];
    const float* b4    = (const float*)d_in[11];
    const float* bias4 = (const float*)d_in[12];
    const float* thr4  = (const float*)d_in[13];
    float* out = (float*)d_out;
    float* ws  = (float*)d_ws;

    hipLaunchKernelGGL(snn_prep, dim3(1024), dim3(256), 0, stream,
                       W2, W3, W4, b1, bias1, b2, bias2, b3, bias3, b4, bias4, ws);
    hipLaunchKernelGGL(snn_main, dim3(B_ROWS), dim3(256), 0, stream,
                       x, W1, ws, thr4, out);
}